// Round 6
// baseline (572.627 us; speedup 1.0000x reference)
//
#include <hip/hip_runtime.h>

#define D 64
#define KCODES 1024
#define MARGIN 1.5f      // worst-case fp16 distance-gap error <= ~0.64; 2.3x cushion
#define FLAG_CAP 16384

typedef _Float16 f16x8 __attribute__((ext_vector_type(8)));
typedef float f32x4 __attribute__((ext_vector_type(4)));

// ws layout:
//   [0, 8KB)                 e2[1024] fp32 + zeroed prefetch pad
//   [8KB, 8KB+132KB)         ehf[1024*64] fp16 + prefetch pad (t=63 reads to +130KB)
//   [143360, +64)            flag counter
//   [143424, +64KB)          flag list
#define WS_E2 0
#define WS_EHF 8192
#define WS_CNT 143360
#define WS_FLAGS 143424

// k0: exact fp32 e2 (proven) + fp16 codebook cast + counter zero.
__global__ __launch_bounds__(256) void prep_kernel(const float* __restrict__ emb,
                                                   float* __restrict__ e2,
                                                   _Float16* __restrict__ ehf,
                                                   unsigned int* __restrict__ counter) {
    int t = blockIdx.x * 256 + threadIdx.x;
    if (t == 0) *counter = 0u;
    if (t < KCODES) {
        const float4* ep = (const float4*)(emb + (size_t)t * D);
        float s0 = 0.f, s1 = 0.f, s2 = 0.f, s3 = 0.f;
#pragma unroll
        for (int i = 0; i < 16; ++i) {
            float4 v = ep[i];
            s0 = fmaf(v.x, v.x, s0);
            s1 = fmaf(v.y, v.y, s1);
            s2 = fmaf(v.z, v.z, s2);
            s3 = fmaf(v.w, v.w, s3);
        }
        e2[t] = (s0 + s1) + (s2 + s3);
    }
    if (t < 16) e2[KCODES + t] = 0.f;   // e2 prefetch pad
    ehf[t] = (_Float16)emb[t];
}

// k1: fp16-MFMA approx argmin + margin flag + fused epilogue.
// Block = 4 waves x 32 rows; grid = 1024 blocks. NOTE: no min-waves clause in
// launch_bounds -- round 4/5 evidence: (256,4) makes the compiler pick a
// 64-VGPR budget and spill the K-loop state to scratch. Natural pressure
// ~100 VGPR -> ~5 waves/SIMD with zero spill.
__global__ __launch_bounds__(256) void vq_kernel(
    const float* __restrict__ x, const float* __restrict__ emb,
    const float* __restrict__ e2, const _Float16* __restrict__ ehf,
    float* __restrict__ out_q, float* __restrict__ out_idx,
    float* __restrict__ out_loss, unsigned int* __restrict__ counter,
    int* __restrict__ flaglist) {
    __shared__ int s_bi[128];
    const int tid = threadIdx.x;
    const int lane = tid & 63;
    const int wave = __builtin_amdgcn_readfirstlane(tid >> 6);
    const int quad = lane >> 4;
    const int l15 = lane & 15;
    const int rowBase = blockIdx.x * 128 + wave * 32;

    // A fragments: 2 rowsets x 2 K-chunks, fp16. A[m=lane&15][k=quad*8+j].
    f16x8 a[2][2];
#pragma unroll
    for (int rs = 0; rs < 2; ++rs) {
        const float* xr = x + (size_t)(rowBase + rs * 16 + l15) * D;
#pragma unroll
        for (int c = 0; c < 2; ++c) {
            const float4* p = (const float4*)(xr + c * 32 + quad * 8);
            float4 f0 = p[0], f1 = p[1];
            f16x8 h;
            h[0] = (_Float16)f0.x; h[1] = (_Float16)f0.y;
            h[2] = (_Float16)f0.z; h[3] = (_Float16)f0.w;
            h[4] = (_Float16)f1.x; h[5] = (_Float16)f1.y;
            h[6] = (_Float16)f1.z; h[7] = (_Float16)f1.w;
            a[rs][c] = h;
        }
    }

    float m1[2][4], m2[2][4];
    int i1[2][4];
#pragma unroll
    for (int rs = 0; rs < 2; ++rs)
#pragma unroll
        for (int r = 0; r < 4; ++r) {
            m1[rs][r] = 3.4e38f;
            m2[rs][r] = 3.4e38f;
            i1[rs][r] = 0;
        }

    // B: code t*16+l15, B[n=l15][k=quad*8+j]; register-rotated prefetch of
    // tile t+1 (pads make the final overrun-read safe; values unused).
    const _Float16* bbase = ehf + (size_t)l15 * D + quad * 8;
    f16x8 nb0 = *(const f16x8*)(bbase);
    f16x8 nb1 = *(const f16x8*)(bbase + 32);
    float ne2 = e2[l15];
    for (int t = 0; t < 64; ++t) {
        f16x8 b0 = nb0, b1 = nb1;
        float e2v = ne2;
        const _Float16* nb = bbase + (size_t)(t + 1) * 16 * D;
        nb0 = *(const f16x8*)(nb);
        nb1 = *(const f16x8*)(nb + 32);
        ne2 = e2[(t + 1) * 16 + l15];
        const int code = (t << 4) + l15;
#pragma unroll
        for (int rs = 0; rs < 2; ++rs) {
            f32x4 acc = {0.f, 0.f, 0.f, 0.f};
            acc = __builtin_amdgcn_mfma_f32_16x16x32_f16(a[rs][0], b0, acc, 0, 0, 0);
            acc = __builtin_amdgcn_mfma_f32_16x16x32_f16(a[rs][1], b1, acc, 0, 0, 0);
#pragma unroll
            for (int r = 0; r < 4; ++r) {
                float v = fmaf(-2.0f, acc[r], e2v);
                bool take = v < m1[rs][r];               // ascending t: first-min
                i1[rs][r] = take ? code : i1[rs][r];
                m2[rs][r] = fminf(m2[rs][r], fmaxf(m1[rs][r], v));
                m1[rs][r] = fminf(m1[rs][r], v);
            }
        }
    }

    // Merge across the 16 code-lanes.
#pragma unroll
    for (int rs = 0; rs < 2; ++rs)
#pragma unroll
        for (int r = 0; r < 4; ++r) {
            float v1 = m1[rs][r], v2 = m2[rs][r];
            int ix = i1[rs][r];
#pragma unroll
            for (int mask = 1; mask < 16; mask <<= 1) {
                float o1 = __shfl_xor(v1, mask);
                int oi = __shfl_xor(ix, mask);
                float o2 = __shfl_xor(v2, mask);
                v2 = fminf(fminf(v2, o2), fmaxf(v1, o1));   // union 2nd-min
                bool take = (o1 < v1) || (o1 == v1 && oi < ix);
                v1 = take ? o1 : v1;
                ix = take ? oi : ix;
            }
            m1[rs][r] = v1;
            m2[rs][r] = v2;
            i1[rs][r] = ix;
        }

    if (l15 == 0) {   // writer lanes: rows quad*4+r of each rowset
#pragma unroll
        for (int rs = 0; rs < 2; ++rs)
#pragma unroll
            for (int r = 0; r < 4; ++r) {
                int lrow = wave * 32 + rs * 16 + quad * 4 + r;
                s_bi[lrow] = i1[rs][r];
                if (m2[rs][r] - m1[rs][r] < MARGIN) {
                    unsigned int slot = atomicAdd(counter, 1u);
                    if (slot < FLAG_CAP) flaglist[slot] = blockIdx.x * 128 + lrow;
                }
            }
    }
    __syncthreads();

    // Fused epilogue (proven bit-exact): one row per thread.
    if (tid < 128) {
        const int row = blockIdx.x * 128 + tid;
        const int bi = s_bi[tid];
        const float4* qp = (const float4*)(emb + (size_t)bi * D);
        const float4* xp = (const float4*)(x + (size_t)row * D);
        float4* oq = (float4*)(out_q + (size_t)row * D);
        float l0 = 0.f, l1 = 0.f, l2 = 0.f, l3 = 0.f;
#pragma unroll
        for (int i = 0; i < 16; ++i) {
            float4 q = qp[i];
            float4 xv = xp[i];
            float a0 = q.x - xv.x, a1 = q.y - xv.y, a2 = q.z - xv.z, a3 = q.w - xv.w;
            l0 = fmaf(a0, a0, l0);
            l1 = fmaf(a1, a1, l1);
            l2 = fmaf(a2, a2, l2);
            l3 = fmaf(a3, a3, l3);
            float4 o;
            o.x = xv.x + a0;
            o.y = xv.y + a1;
            o.z = xv.z + a2;
            o.w = xv.w + a3;
            oq[i] = o;
        }
        float s = (l0 + l1) + (l2 + l3);
        out_idx[row] = (float)bi;
        out_loss[row] = s + 0.25f * s;
    }
}

// k2: exact fp32 rescore, one BLOCK per flagged row (grid-stride). x row in
// LDS (broadcast reads, conflict-free); thread t handles codes 4t..4t+3 with
// i-outer / code-inner loop so each LDS read feeds 4 accumulators. Per-thread
// state ~30 VGPRs -> no spill (round-5 fix: xv[64] per lane spilled to
// cached scratch and cost 227 us).
__global__ __launch_bounds__(256) void rescore_kernel(
    const float* __restrict__ x, const float* __restrict__ emb,
    const float* __restrict__ e2, float* __restrict__ out_q,
    float* __restrict__ out_idx, float* __restrict__ out_loss,
    const unsigned int* __restrict__ counter, const int* __restrict__ flaglist) {
    __shared__ float xs[D];
    __shared__ float s_d[256];
    __shared__ int s_i[256];
    unsigned int n = *counter;
    if (n > FLAG_CAP) n = FLAG_CAP;
    const int tid = threadIdx.x;

    for (unsigned int f = blockIdx.x; f < n; f += gridDim.x) {
        const int row = flaglist[f];
        __syncthreads();   // protect xs/s_d/s_i reuse across grid-stride iters
        if (tid < 16) ((float4*)xs)[tid] = ((const float4*)(x + (size_t)row * D))[tid];
        __syncthreads();

        const int k0 = tid * 4;   // 4 consecutive codes per thread
        float d0[4] = {0.f, 0.f, 0.f, 0.f};
        float d1[4] = {0.f, 0.f, 0.f, 0.f};
        float d2[4] = {0.f, 0.f, 0.f, 0.f};
        float d3[4] = {0.f, 0.f, 0.f, 0.f};
        const float4* eb = (const float4*)(emb + (size_t)k0 * D);
#pragma unroll 4
        for (int i = 0; i < 16; ++i) {
            float4 xv = ((const float4*)xs)[i];
#pragma unroll
            for (int c = 0; c < 4; ++c) {
                float4 ev = eb[c * 16 + i];
                d0[c] = fmaf(xv.x, ev.x, d0[c]);
                d1[c] = fmaf(xv.y, ev.y, d1[c]);
                d2[c] = fmaf(xv.z, ev.z, d2[c]);
                d3[c] = fmaf(xv.w, ev.w, d3[c]);
            }
        }
        float bd = 3.4e38f;
        int bi = 0;
#pragma unroll
        for (int c = 0; c < 4; ++c) {   // ascending k: first-min
            float dist = fmaf(-2.0f, (d0[c] + d1[c]) + (d2[c] + d3[c]), e2[k0 + c]);
            if (dist < bd) { bd = dist; bi = k0 + c; }
        }
        s_d[tid] = bd;
        s_i[tid] = bi;
        __syncthreads();
        for (int s = 128; s > 0; s >>= 1) {   // lex-min: global first-min
            if (tid < s) {
                float od = s_d[tid + s];
                int oi = s_i[tid + s];
                if (od < s_d[tid] || (od == s_d[tid] && oi < s_i[tid])) {
                    s_d[tid] = od;
                    s_i[tid] = oi;
                }
            }
            __syncthreads();
        }
        if (tid == 0) {   // bit-identical epilogue for this row
            const int fbi = s_i[0];
            const float4* qp = (const float4*)(emb + (size_t)fbi * D);
            const float4* xp = (const float4*)xs;   // same bits as global x row
            float4* oq = (float4*)(out_q + (size_t)row * D);
            float l0 = 0.f, l1 = 0.f, l2 = 0.f, l3 = 0.f;
#pragma unroll
            for (int i = 0; i < 16; ++i) {
                float4 q = qp[i];
                float4 xw = xp[i];
                float a0 = q.x - xw.x, a1 = q.y - xw.y, a2 = q.z - xw.z, a3 = q.w - xw.w;
                l0 = fmaf(a0, a0, l0);
                l1 = fmaf(a1, a1, l1);
                l2 = fmaf(a2, a2, l2);
                l3 = fmaf(a3, a3, l3);
                float4 o;
                o.x = xw.x + a0;
                o.y = xw.y + a1;
                o.z = xw.z + a2;
                o.w = xw.w + a3;
                oq[i] = o;
            }
            float s = (l0 + l1) + (l2 + l3);
            out_idx[row] = (float)fbi;
            out_loss[row] = s + 0.25f * s;
        }
    }
}

extern "C" void kernel_launch(void* const* d_in, const int* in_sizes, int n_in,
                              void* d_out, int out_size, void* d_ws, size_t ws_size,
                              hipStream_t stream) {
    const float* x = (const float*)d_in[0];     // [B,T,D] fp32
    const float* emb = (const float*)d_in[1];   // [K,D] fp32
    const int nrows = in_sizes[0] / D;          // 131072

    float* out_q = (float*)d_out;
    float* out_idx = out_q + (size_t)nrows * D;
    float* out_loss = out_idx + nrows;

    char* ws = (char*)d_ws;
    float* e2 = (float*)(ws + WS_E2);
    _Float16* ehf = (_Float16*)(ws + WS_EHF);
    unsigned int* counter = (unsigned int*)(ws + WS_CNT);
    int* flaglist = (int*)(ws + WS_FLAGS);

    prep_kernel<<<(KCODES * D) / 256, 256, 0, stream>>>(emb, e2, ehf, counter);
    vq_kernel<<<nrows / 128, 256, 0, stream>>>(x, emb, e2, ehf, out_q, out_idx,
                                               out_loss, counter, flaglist);
    rescore_kernel<<<2048, 256, 0, stream>>>(x, emb, e2, out_q, out_idx, out_loss,
                                             counter, flaglist);
}

// Round 7
// 287.871 us; speedup vs baseline: 1.9892x; 1.9892x over previous
//
#include <hip/hip_runtime.h>
#include <hip/hip_bf16.h>

#define D 64
#define KCODES 1024
#define MARGIN 0.25f     // bf16-split dist error <= ~0.01; round-3-proven margin
#define FLAG_CAP 8192

typedef __attribute__((ext_vector_type(8))) short bf16x8;
typedef __attribute__((ext_vector_type(4))) float f32x4;

// ws layout (<= 308KB; round-3 proved >=331KB available):
//   [0, 8KB)             e2[1024] fp32 + zeroed prefetch pad
//   [8KB, 139264)        ehi[1024*64] bf16  (prefetch overrun lands in elo: harmless)
//   [139264, 270336)     elo[1024*64] bf16  (overrun lands in 4KB pad below)
//   [270336, 274432)     pad
//   [274432, +64)        flag counter
//   [274496, +32KB)      flag list
#define WS_E2 0
#define WS_EHI 8192
#define WS_ELO 139264
#define WS_CNT 274432
#define WS_FLAGS 274496

__device__ inline unsigned short f2bf(float f) {
    union { __hip_bfloat16 h; unsigned short s; } cv;
    cv.h = __float2bfloat16(f);
    return cv.s;
}
__device__ inline float bf2f(unsigned short v) {
    union { unsigned short s; __hip_bfloat16 h; } cv;
    cv.s = v;
    return __bfloat162float(cv.h);
}

// k0: exact fp32 e2 (proven) + bf16 hi/lo split of codebook + counter zero.
__global__ __launch_bounds__(256) void prep_kernel(const float* __restrict__ emb,
                                                   float* __restrict__ e2,
                                                   unsigned short* __restrict__ ehi,
                                                   unsigned short* __restrict__ elo,
                                                   unsigned int* __restrict__ counter) {
    int t = blockIdx.x * 256 + threadIdx.x;
    if (t == 0) *counter = 0u;
    if (t < KCODES) {
        const float4* ep = (const float4*)(emb + (size_t)t * D);
        float s0 = 0.f, s1 = 0.f, s2 = 0.f, s3 = 0.f;
#pragma unroll
        for (int i = 0; i < 16; ++i) {
            float4 v = ep[i];
            s0 = fmaf(v.x, v.x, s0);
            s1 = fmaf(v.y, v.y, s1);
            s2 = fmaf(v.z, v.z, s2);
            s3 = fmaf(v.w, v.w, s3);
        }
        e2[t] = (s0 + s1) + (s2 + s3);
    }
    if (t < 16) e2[KCODES + t] = 0.f;   // e2 prefetch pad
    float v = emb[t];
    unsigned short h = f2bf(v);
    ehi[t] = h;
    elo[t] = f2bf(v - bf2f(h));   // exact residual (Sterbenz)
}

// k1: bf16-split MFMA argmin (round-3-proven numerics, MARGIN 0.25 -> n~1300)
// + LDS-batched flags (ONE global atomic per block; round-6's 8000 per-row
// return-value atomics serialized ~100+us) + fused epilogue.
// Block = 4 waves x 32 rows; grid = 1024 blocks; B prefetch rotation.
__global__ __launch_bounds__(256) void vq_kernel(
    const float* __restrict__ x, const float* __restrict__ emb,
    const float* __restrict__ e2, const unsigned short* __restrict__ ehi,
    const unsigned short* __restrict__ elo, float* __restrict__ out_q,
    float* __restrict__ out_idx, float* __restrict__ out_loss,
    unsigned int* __restrict__ counter, int* __restrict__ flaglist) {
    __shared__ int s_bi[128];
    __shared__ int s_flag[128];
    __shared__ int s_nflag;
    __shared__ unsigned int s_base;

    const int tid = threadIdx.x;
    const int lane = tid & 63;
    const int wave = __builtin_amdgcn_readfirstlane(tid >> 6);
    const int quad = lane >> 4;
    const int l15 = lane & 15;
    const int rowBase = blockIdx.x * 128 + wave * 32;

    if (tid == 0) s_nflag = 0;

    // A fragments: 2 rowsets x 2 K-chunks x (hi,lo). A[m=lane&15][k=quad*8+j].
    bf16x8 ah[2][2], al[2][2];
#pragma unroll
    for (int rs = 0; rs < 2; ++rs) {
        const float* xr = x + (size_t)(rowBase + rs * 16 + l15) * D;
#pragma unroll
        for (int c = 0; c < 2; ++c) {
            const float4* p = (const float4*)(xr + c * 32 + quad * 8);
            float4 f0 = p[0], f1 = p[1];
            float f[8] = {f0.x, f0.y, f0.z, f0.w, f1.x, f1.y, f1.z, f1.w};
            bf16x8 h, l;
#pragma unroll
            for (int j = 0; j < 8; ++j) {
                unsigned short hu = f2bf(f[j]);
                h[j] = (short)hu;
                l[j] = (short)f2bf(f[j] - bf2f(hu));
            }
            ah[rs][c] = h;
            al[rs][c] = l;
        }
    }
    __syncthreads();   // publish s_nflag=0 before writer-lane LDS atomics

    float m1[2][4], m2[2][4];
    int i1[2][4];
#pragma unroll
    for (int rs = 0; rs < 2; ++rs)
#pragma unroll
        for (int r = 0; r < 4; ++r) {
            m1[rs][r] = 3.4e38f;
            m2[rs][r] = 3.4e38f;
            i1[rs][r] = 0;
        }

    // B: code t*16+l15, B[n=l15][k=quad*8+j]; register-rotated prefetch of
    // tile t+1 (pad/adjacent regions make the final overrun-read safe).
    const size_t boff = (size_t)l15 * D + quad * 8;
    const unsigned short* hbase = ehi + boff;
    const unsigned short* lbase = elo + boff;
    bf16x8 nh0 = *(const bf16x8*)(hbase);
    bf16x8 nh1 = *(const bf16x8*)(hbase + 32);
    bf16x8 nl0 = *(const bf16x8*)(lbase);
    bf16x8 nl1 = *(const bf16x8*)(lbase + 32);
    float ne2 = e2[l15];
    for (int t = 0; t < 64; ++t) {
        bf16x8 bh0 = nh0, bh1 = nh1, bl0 = nl0, bl1 = nl1;
        float e2v = ne2;
        const size_t noff = (size_t)(t + 1) * 16 * D;
        nh0 = *(const bf16x8*)(hbase + noff);
        nh1 = *(const bf16x8*)(hbase + noff + 32);
        nl0 = *(const bf16x8*)(lbase + noff);
        nl1 = *(const bf16x8*)(lbase + noff + 32);
        ne2 = e2[(t + 1) * 16 + l15];
        const int code = (t << 4) + l15;
#pragma unroll
        for (int rs = 0; rs < 2; ++rs) {
            f32x4 acc = {0.f, 0.f, 0.f, 0.f};
            // round-3-proven accumulation order: hh, hl, lh per K-chunk
            acc = __builtin_amdgcn_mfma_f32_16x16x32_bf16(ah[rs][0], bh0, acc, 0, 0, 0);
            acc = __builtin_amdgcn_mfma_f32_16x16x32_bf16(ah[rs][0], bl0, acc, 0, 0, 0);
            acc = __builtin_amdgcn_mfma_f32_16x16x32_bf16(al[rs][0], bh0, acc, 0, 0, 0);
            acc = __builtin_amdgcn_mfma_f32_16x16x32_bf16(ah[rs][1], bh1, acc, 0, 0, 0);
            acc = __builtin_amdgcn_mfma_f32_16x16x32_bf16(ah[rs][1], bl1, acc, 0, 0, 0);
            acc = __builtin_amdgcn_mfma_f32_16x16x32_bf16(al[rs][1], bh1, acc, 0, 0, 0);
#pragma unroll
            for (int r = 0; r < 4; ++r) {
                float v = fmaf(-2.0f, acc[r], e2v);
                bool take = v < m1[rs][r];               // ascending t: first-min
                i1[rs][r] = take ? code : i1[rs][r];
                m2[rs][r] = fminf(m2[rs][r], fmaxf(m1[rs][r], v));
                m1[rs][r] = fminf(m1[rs][r], v);
            }
        }
    }

    // Merge across the 16 code-lanes.
#pragma unroll
    for (int rs = 0; rs < 2; ++rs)
#pragma unroll
        for (int r = 0; r < 4; ++r) {
            float v1 = m1[rs][r], v2 = m2[rs][r];
            int ix = i1[rs][r];
#pragma unroll
            for (int mask = 1; mask < 16; mask <<= 1) {
                float o1 = __shfl_xor(v1, mask);
                int oi = __shfl_xor(ix, mask);
                float o2 = __shfl_xor(v2, mask);
                v2 = fminf(fminf(v2, o2), fmaxf(v1, o1));   // union 2nd-min
                bool take = (o1 < v1) || (o1 == v1 && oi < ix);
                v1 = take ? o1 : v1;
                ix = take ? oi : ix;
            }
            m1[rs][r] = v1;
            m2[rs][r] = v2;
            i1[rs][r] = ix;
        }

    if (l15 == 0) {   // writer lanes: rows quad*4+r of each rowset -> LDS flags
#pragma unroll
        for (int rs = 0; rs < 2; ++rs)
#pragma unroll
            for (int r = 0; r < 4; ++r) {
                int lrow = wave * 32 + rs * 16 + quad * 4 + r;
                s_bi[lrow] = i1[rs][r];
                if (m2[rs][r] - m1[rs][r] < MARGIN) {
                    int slot = atomicAdd(&s_nflag, 1);   // LDS atomic: fast
                    s_flag[slot] = lrow;
                }
            }
    }
    __syncthreads();
    if (tid == 0) s_base = (s_nflag > 0) ? atomicAdd(counter, (unsigned)s_nflag) : 0u;
    __syncthreads();
    const int nf = s_nflag;
    if (tid < nf) {
        unsigned int slot = s_base + tid;
        if (slot < FLAG_CAP) flaglist[slot] = blockIdx.x * 128 + s_flag[tid];
    }

    // Fused epilogue (proven bit-exact): one row per thread.
    if (tid < 128) {
        const int row = blockIdx.x * 128 + tid;
        const int bi = s_bi[tid];
        const float4* qp = (const float4*)(emb + (size_t)bi * D);
        const float4* xp = (const float4*)(x + (size_t)row * D);
        float4* oq = (float4*)(out_q + (size_t)row * D);
        float l0 = 0.f, l1 = 0.f, l2 = 0.f, l3 = 0.f;
#pragma unroll
        for (int i = 0; i < 16; ++i) {
            float4 q = qp[i];
            float4 xv = xp[i];
            float a0 = q.x - xv.x, a1 = q.y - xv.y, a2 = q.z - xv.z, a3 = q.w - xv.w;
            l0 = fmaf(a0, a0, l0);
            l1 = fmaf(a1, a1, l1);
            l2 = fmaf(a2, a2, l2);
            l3 = fmaf(a3, a3, l3);
            float4 o;
            o.x = xv.x + a0;
            o.y = xv.y + a1;
            o.z = xv.z + a2;
            o.w = xv.w + a3;
            oq[i] = o;
        }
        float s = (l0 + l1) + (l2 + l3);
        out_idx[row] = (float)bi;
        out_loss[row] = s + 0.25f * s;
    }
}

// k2: exact fp32 rescore (round-6 structure verbatim, proven bits): block per
// flagged row, x in LDS, thread = 4 codes. At n~1300 the gather cost is ~6x
// smaller than round 6's. Lex-min reduction preserves jnp.argmin first-min.
__global__ __launch_bounds__(256) void rescore_kernel(
    const float* __restrict__ x, const float* __restrict__ emb,
    const float* __restrict__ e2, float* __restrict__ out_q,
    float* __restrict__ out_idx, float* __restrict__ out_loss,
    const unsigned int* __restrict__ counter, const int* __restrict__ flaglist) {
    __shared__ float xs[D];
    __shared__ float s_d[256];
    __shared__ int s_i[256];
    unsigned int n = *counter;
    if (n > FLAG_CAP) n = FLAG_CAP;
    const int tid = threadIdx.x;

    for (unsigned int f = blockIdx.x; f < n; f += gridDim.x) {
        const int row = flaglist[f];
        __syncthreads();   // protect xs/s_d/s_i reuse across grid-stride iters
        if (tid < 16) ((float4*)xs)[tid] = ((const float4*)(x + (size_t)row * D))[tid];
        __syncthreads();

        const int k0 = tid * 4;
        float d0[4] = {0.f, 0.f, 0.f, 0.f};
        float d1[4] = {0.f, 0.f, 0.f, 0.f};
        float d2[4] = {0.f, 0.f, 0.f, 0.f};
        float d3[4] = {0.f, 0.f, 0.f, 0.f};
        const float4* eb = (const float4*)(emb + (size_t)k0 * D);
#pragma unroll 4
        for (int i = 0; i < 16; ++i) {
            float4 xv = ((const float4*)xs)[i];
#pragma unroll
            for (int c = 0; c < 4; ++c) {
                float4 ev = eb[c * 16 + i];
                d0[c] = fmaf(xv.x, ev.x, d0[c]);
                d1[c] = fmaf(xv.y, ev.y, d1[c]);
                d2[c] = fmaf(xv.z, ev.z, d2[c]);
                d3[c] = fmaf(xv.w, ev.w, d3[c]);
            }
        }
        float bd = 3.4e38f;
        int bi = 0;
#pragma unroll
        for (int c = 0; c < 4; ++c) {   // ascending k: first-min
            float dist = fmaf(-2.0f, (d0[c] + d1[c]) + (d2[c] + d3[c]), e2[k0 + c]);
            if (dist < bd) { bd = dist; bi = k0 + c; }
        }
        s_d[tid] = bd;
        s_i[tid] = bi;
        __syncthreads();
        for (int s = 128; s > 0; s >>= 1) {   // lex-min: global first-min
            if (tid < s) {
                float od = s_d[tid + s];
                int oi = s_i[tid + s];
                if (od < s_d[tid] || (od == s_d[tid] && oi < s_i[tid])) {
                    s_d[tid] = od;
                    s_i[tid] = oi;
                }
            }
            __syncthreads();
        }
        if (tid == 0) {   // bit-identical epilogue for this row
            const int fbi = s_i[0];
            const float4* qp = (const float4*)(emb + (size_t)fbi * D);
            const float4* xp = (const float4*)xs;
            float4* oq = (float4*)(out_q + (size_t)row * D);
            float l0 = 0.f, l1 = 0.f, l2 = 0.f, l3 = 0.f;
#pragma unroll
            for (int i = 0; i < 16; ++i) {
                float4 q = qp[i];
                float4 xw = xp[i];
                float a0 = q.x - xw.x, a1 = q.y - xw.y, a2 = q.z - xw.z, a3 = q.w - xw.w;
                l0 = fmaf(a0, a0, l0);
                l1 = fmaf(a1, a1, l1);
                l2 = fmaf(a2, a2, l2);
                l3 = fmaf(a3, a3, l3);
                float4 o;
                o.x = xw.x + a0;
                o.y = xw.y + a1;
                o.z = xw.z + a2;
                o.w = xw.w + a3;
                oq[i] = o;
            }
            float s = (l0 + l1) + (l2 + l3);
            out_idx[row] = (float)fbi;
            out_loss[row] = s + 0.25f * s;
        }
    }
}

extern "C" void kernel_launch(void* const* d_in, const int* in_sizes, int n_in,
                              void* d_out, int out_size, void* d_ws, size_t ws_size,
                              hipStream_t stream) {
    const float* x = (const float*)d_in[0];     // [B,T,D] fp32
    const float* emb = (const float*)d_in[1];   // [K,D] fp32
    const int nrows = in_sizes[0] / D;          // 131072

    float* out_q = (float*)d_out;
    float* out_idx = out_q + (size_t)nrows * D;
    float* out_loss = out_idx + nrows;

    char* ws = (char*)d_ws;
    float* e2 = (float*)(ws + WS_E2);
    unsigned short* ehi = (unsigned short*)(ws + WS_EHI);
    unsigned short* elo = (unsigned short*)(ws + WS_ELO);
    unsigned int* counter = (unsigned int*)(ws + WS_CNT);
    int* flaglist = (int*)(ws + WS_FLAGS);

    prep_kernel<<<(KCODES * D) / 256, 256, 0, stream>>>(emb, e2, ehi, elo, counter);
    vq_kernel<<<nrows / 128, 256, 0, stream>>>(x, emb, e2, ehi, elo, out_q,
                                               out_idx, out_loss, counter, flaglist);
    rescore_kernel<<<2048, 256, 0, stream>>>(x, emb, e2, out_q, out_idx, out_loss,
                                             counter, flaglist);
}

// Round 8
// 216.950 us; speedup vs baseline: 2.6394x; 1.3269x over previous
//
#include <hip/hip_runtime.h>
#include <hip/hip_bf16.h>

#define D 64
#define KCODES 1024
#define MARGIN 0.25f     // bf16-split dist error <= ~0.01; round-3/7-proven margin
#define FLAG_CAP 8192

typedef __attribute__((ext_vector_type(8))) short bf16x8;
typedef __attribute__((ext_vector_type(4))) float f32x4;

// ws layout (same as round 7):
#define WS_E2 0
#define WS_EHI 8192
#define WS_ELO 139264
#define WS_CNT 274432
#define WS_FLAGS 274496

__device__ inline unsigned short f2bf(float f) {
    union { __hip_bfloat16 h; unsigned short s; } cv;
    cv.h = __float2bfloat16(f);
    return cv.s;
}
__device__ inline float bf2f(unsigned short v) {
    union { unsigned short s; __hip_bfloat16 h; } cv;
    cv.s = v;
    return __bfloat162float(cv.h);
}

// k0: exact fp32 e2 (proven) + bf16 hi/lo split of codebook + counter zero.
__global__ __launch_bounds__(256) void prep_kernel(const float* __restrict__ emb,
                                                   float* __restrict__ e2,
                                                   unsigned short* __restrict__ ehi,
                                                   unsigned short* __restrict__ elo,
                                                   unsigned int* __restrict__ counter) {
    int t = blockIdx.x * 256 + threadIdx.x;
    if (t == 0) *counter = 0u;
    if (t < KCODES) {
        const float4* ep = (const float4*)(emb + (size_t)t * D);
        float s0 = 0.f, s1 = 0.f, s2 = 0.f, s3 = 0.f;
#pragma unroll
        for (int i = 0; i < 16; ++i) {
            float4 v = ep[i];
            s0 = fmaf(v.x, v.x, s0);
            s1 = fmaf(v.y, v.y, s1);
            s2 = fmaf(v.z, v.z, s2);
            s3 = fmaf(v.w, v.w, s3);
        }
        e2[t] = (s0 + s1) + (s2 + s3);
    }
    float v = emb[t];
    unsigned short h = f2bf(v);
    ehi[t] = h;
    elo[t] = f2bf(v - bf2f(h));   // exact residual (Sterbenz)
}

// k1: bf16-split MFMA argmin with LDS-staged, double-buffered codebook.
// R7 lesson: per-wave global B reads made the K-loop L1-delivery-bound
// (wall ~ total B-load iterations; MfmaUtil 11%). Fix: stage each 64-code
// super-tile (hi+lo, 16KB) ONCE per block in fragment-order so every
// ds_read_b128 / ds_write_b128 is the contiguous lane*16 happy path.
// Block = 4 waves x 32 rows = 128 rows; grid = 1024 blocks (4/CU).
__global__ __launch_bounds__(256) void vq_kernel(
    const float* __restrict__ x, const float* __restrict__ emb,
    const float* __restrict__ e2, const unsigned short* __restrict__ ehi,
    const unsigned short* __restrict__ elo, float* __restrict__ out_q,
    float* __restrict__ out_idx, float* __restrict__ out_loss,
    unsigned int* __restrict__ counter, int* __restrict__ flaglist) {
    __shared__ uint4 s_b[2][1024];     // 2 x 16KB: [subtile(4)][r(4)][lane(64)]
    __shared__ float s_e2[KCODES];     // 4KB
    __shared__ int s_bi[128];
    __shared__ int s_flag[128];
    __shared__ int s_nflag;
    __shared__ unsigned int s_base;

    const int tid = threadIdx.x;
    const int lane = tid & 63;
    const int wave = __builtin_amdgcn_readfirstlane(tid >> 6);
    const int quad = lane >> 4;
    const int l15 = lane & 15;
    const int rowBase = blockIdx.x * 128 + wave * 32;

    if (tid == 0) s_nflag = 0;

    // Staging source map (verified bijection with the read side):
    //   thread tid, chunk i: LDS slot = i*256 + tid  <->  global chunk
    //   (code = sT*64 + i*16 + (tid&15), part = (tid>>6)*4 + ((tid>>4)&3)).
    //   part<8 -> ehi line (tid>>6 in {0,1}), else elo. Wave reads 16 full
    //   64B lines per instruction (dense); LDS write is lane*16 contiguous.
    const int scode = tid & 15;
    const int part = (tid >> 6) * 4 + ((tid >> 4) & 3);
    const unsigned short* srcbase = ((part < 8) ? ehi : elo) + (size_t)scode * D + (part & 7) * 8;

    // e2 -> LDS
#pragma unroll
    for (int i = 0; i < 4; ++i) s_e2[i * 256 + tid] = e2[i * 256 + tid];

    // A fragments: 2 rowsets x 2 K-chunks x (hi,lo). A[m=lane&15][k=quad*8+j].
    bf16x8 ah[2][2], al[2][2];
#pragma unroll
    for (int rs = 0; rs < 2; ++rs) {
        const float* xr = x + (size_t)(rowBase + rs * 16 + l15) * D;
#pragma unroll
        for (int c = 0; c < 2; ++c) {
            const float4* p = (const float4*)(xr + c * 32 + quad * 8);
            float4 f0 = p[0], f1 = p[1];
            float f[8] = {f0.x, f0.y, f0.z, f0.w, f1.x, f1.y, f1.z, f1.w};
            bf16x8 h, l;
#pragma unroll
            for (int j = 0; j < 8; ++j) {
                unsigned short hu = f2bf(f[j]);
                h[j] = (short)hu;
                l[j] = (short)f2bf(f[j] - bf2f(hu));
            }
            ah[rs][c] = h;
            al[rs][c] = l;
        }
    }

    float m1[2][4], m2[2][4];
    int i1[2][4];
#pragma unroll
    for (int rs = 0; rs < 2; ++rs)
#pragma unroll
        for (int r = 0; r < 4; ++r) {
            m1[rs][r] = 3.4e38f;
            m2[rs][r] = 3.4e38f;
            i1[rs][r] = 0;
        }

    // Stage super-tile 0 into buffer 0.
    {
        uint4 v[4];
#pragma unroll
        for (int i = 0; i < 4; ++i)
            v[i] = *(const uint4*)(srcbase + (size_t)(i * 16) * D);
#pragma unroll
        for (int i = 0; i < 4; ++i) s_b[0][i * 256 + tid] = v[i];
    }
    __syncthreads();

    for (int sT = 0; sT < 16; ++sT) {
        const int buf = sT & 1;
        uint4 nx[4];
        if (sT < 15) {   // issue next super-tile's global loads before compute
#pragma unroll
            for (int i = 0; i < 4; ++i)
                nx[i] = *(const uint4*)(srcbase + (size_t)((sT + 1) * 64 + i * 16) * D);
        }
#pragma unroll
        for (int stt = 0; stt < 4; ++stt) {
            const uint4* bb = &s_b[buf][stt * 256 + lane];
            bf16x8 bh0 = *(const bf16x8*)(bb);          // r=0
            bf16x8 bh1 = *(const bf16x8*)(bb + 64);     // r=1
            bf16x8 bl0 = *(const bf16x8*)(bb + 128);    // r=2
            bf16x8 bl1 = *(const bf16x8*)(bb + 192);    // r=3
            const int code = sT * 64 + stt * 16 + l15;
            const float e2v = s_e2[code];
#pragma unroll
            for (int rs = 0; rs < 2; ++rs) {
                f32x4 acc = {0.f, 0.f, 0.f, 0.f};
                // round-3/7-proven accumulation order: hh, hl, lh per K-chunk
                acc = __builtin_amdgcn_mfma_f32_16x16x32_bf16(ah[rs][0], bh0, acc, 0, 0, 0);
                acc = __builtin_amdgcn_mfma_f32_16x16x32_bf16(ah[rs][0], bl0, acc, 0, 0, 0);
                acc = __builtin_amdgcn_mfma_f32_16x16x32_bf16(al[rs][0], bh0, acc, 0, 0, 0);
                acc = __builtin_amdgcn_mfma_f32_16x16x32_bf16(ah[rs][1], bh1, acc, 0, 0, 0);
                acc = __builtin_amdgcn_mfma_f32_16x16x32_bf16(ah[rs][1], bl1, acc, 0, 0, 0);
                acc = __builtin_amdgcn_mfma_f32_16x16x32_bf16(al[rs][1], bh1, acc, 0, 0, 0);
#pragma unroll
                for (int r = 0; r < 4; ++r) {
                    float v = fmaf(-2.0f, acc[r], e2v);
                    bool take = v < m1[rs][r];           // ascending code: first-min
                    i1[rs][r] = take ? code : i1[rs][r];
                    m2[rs][r] = fminf(m2[rs][r], fmaxf(m1[rs][r], v));
                    m1[rs][r] = fminf(m1[rs][r], v);
                }
            }
        }
        if (sT < 15) {   // land next tile into the other buffer
#pragma unroll
            for (int i = 0; i < 4; ++i) s_b[buf ^ 1][i * 256 + tid] = nx[i];
        }
        __syncthreads();
    }

    // Merge across the 16 code-lanes (proven).
#pragma unroll
    for (int rs = 0; rs < 2; ++rs)
#pragma unroll
        for (int r = 0; r < 4; ++r) {
            float v1 = m1[rs][r], v2 = m2[rs][r];
            int ix = i1[rs][r];
#pragma unroll
            for (int mask = 1; mask < 16; mask <<= 1) {
                float o1 = __shfl_xor(v1, mask);
                int oi = __shfl_xor(ix, mask);
                float o2 = __shfl_xor(v2, mask);
                v2 = fminf(fminf(v2, o2), fmaxf(v1, o1));   // union 2nd-min
                bool take = (o1 < v1) || (o1 == v1 && oi < ix);
                v1 = take ? o1 : v1;
                ix = take ? oi : ix;
            }
            m1[rs][r] = v1;
            m2[rs][r] = v2;
            i1[rs][r] = ix;
        }

    if (l15 == 0) {   // writer lanes -> LDS flags (batched atomic, proven R7)
#pragma unroll
        for (int rs = 0; rs < 2; ++rs)
#pragma unroll
            for (int r = 0; r < 4; ++r) {
                int lrow = wave * 32 + rs * 16 + quad * 4 + r;
                s_bi[lrow] = i1[rs][r];
                if (m2[rs][r] - m1[rs][r] < MARGIN) {
                    int slot = atomicAdd(&s_nflag, 1);
                    s_flag[slot] = lrow;
                }
            }
    }
    __syncthreads();
    if (tid == 0) s_base = (s_nflag > 0) ? atomicAdd(counter, (unsigned)s_nflag) : 0u;
    __syncthreads();
    const int nf = s_nflag;
    if (tid < nf) {
        unsigned int slot = s_base + tid;
        if (slot < FLAG_CAP) flaglist[slot] = blockIdx.x * 128 + s_flag[tid];
    }

    // Fused epilogue (proven bit-exact): one row per thread.
    if (tid < 128) {
        const int row = blockIdx.x * 128 + tid;
        const int bi = s_bi[tid];
        const float4* qp = (const float4*)(emb + (size_t)bi * D);
        const float4* xp = (const float4*)(x + (size_t)row * D);
        float4* oq = (float4*)(out_q + (size_t)row * D);
        float l0 = 0.f, l1 = 0.f, l2 = 0.f, l3 = 0.f;
#pragma unroll
        for (int i = 0; i < 16; ++i) {
            float4 q = qp[i];
            float4 xv = xp[i];
            float a0 = q.x - xv.x, a1 = q.y - xv.y, a2 = q.z - xv.z, a3 = q.w - xv.w;
            l0 = fmaf(a0, a0, l0);
            l1 = fmaf(a1, a1, l1);
            l2 = fmaf(a2, a2, l2);
            l3 = fmaf(a3, a3, l3);
            float4 o;
            o.x = xv.x + a0;
            o.y = xv.y + a1;
            o.z = xv.z + a2;
            o.w = xv.w + a3;
            oq[i] = o;
        }
        float s = (l0 + l1) + (l2 + l3);
        out_idx[row] = (float)bi;
        out_loss[row] = s + 0.25f * s;
    }
}

// k2: exact fp32 rescore (round-6/7 structure verbatim, proven bits).
__global__ __launch_bounds__(256) void rescore_kernel(
    const float* __restrict__ x, const float* __restrict__ emb,
    const float* __restrict__ e2, float* __restrict__ out_q,
    float* __restrict__ out_idx, float* __restrict__ out_loss,
    const unsigned int* __restrict__ counter, const int* __restrict__ flaglist) {
    __shared__ float xs[D];
    __shared__ float s_d[256];
    __shared__ int s_i[256];
    unsigned int n = *counter;
    if (n > FLAG_CAP) n = FLAG_CAP;
    const int tid = threadIdx.x;

    for (unsigned int f = blockIdx.x; f < n; f += gridDim.x) {
        const int row = flaglist[f];
        __syncthreads();
        if (tid < 16) ((float4*)xs)[tid] = ((const float4*)(x + (size_t)row * D))[tid];
        __syncthreads();

        const int k0 = tid * 4;
        float d0[4] = {0.f, 0.f, 0.f, 0.f};
        float d1[4] = {0.f, 0.f, 0.f, 0.f};
        float d2[4] = {0.f, 0.f, 0.f, 0.f};
        float d3[4] = {0.f, 0.f, 0.f, 0.f};
        const float4* eb = (const float4*)(emb + (size_t)k0 * D);
#pragma unroll 4
        for (int i = 0; i < 16; ++i) {
            float4 xv = ((const float4*)xs)[i];
#pragma unroll
            for (int c = 0; c < 4; ++c) {
                float4 ev = eb[c * 16 + i];
                d0[c] = fmaf(xv.x, ev.x, d0[c]);
                d1[c] = fmaf(xv.y, ev.y, d1[c]);
                d2[c] = fmaf(xv.z, ev.z, d2[c]);
                d3[c] = fmaf(xv.w, ev.w, d3[c]);
            }
        }
        float bd = 3.4e38f;
        int bi = 0;
#pragma unroll
        for (int c = 0; c < 4; ++c) {
            float dist = fmaf(-2.0f, (d0[c] + d1[c]) + (d2[c] + d3[c]), e2[k0 + c]);
            if (dist < bd) { bd = dist; bi = k0 + c; }
        }
        s_d[tid] = bd;
        s_i[tid] = bi;
        __syncthreads();
        for (int s = 128; s > 0; s >>= 1) {
            if (tid < s) {
                float od = s_d[tid + s];
                int oi = s_i[tid + s];
                if (od < s_d[tid] || (od == s_d[tid] && oi < s_i[tid])) {
                    s_d[tid] = od;
                    s_i[tid] = oi;
                }
            }
            __syncthreads();
        }
        if (tid == 0) {
            const int fbi = s_i[0];
            const float4* qp = (const float4*)(emb + (size_t)fbi * D);
            const float4* xp = (const float4*)xs;
            float4* oq = (float4*)(out_q + (size_t)row * D);
            float l0 = 0.f, l1 = 0.f, l2 = 0.f, l3 = 0.f;
#pragma unroll
            for (int i = 0; i < 16; ++i) {
                float4 q = qp[i];
                float4 xw = xp[i];
                float a0 = q.x - xw.x, a1 = q.y - xw.y, a2 = q.z - xw.z, a3 = q.w - xw.w;
                l0 = fmaf(a0, a0, l0);
                l1 = fmaf(a1, a1, l1);
                l2 = fmaf(a2, a2, l2);
                l3 = fmaf(a3, a3, l3);
                float4 o;
                o.x = xw.x + a0;
                o.y = xw.y + a1;
                o.z = xw.z + a2;
                o.w = xw.w + a3;
                oq[i] = o;
            }
            float s = (l0 + l1) + (l2 + l3);
            out_idx[row] = (float)fbi;
            out_loss[row] = s + 0.25f * s;
        }
    }
}

extern "C" void kernel_launch(void* const* d_in, const int* in_sizes, int n_in,
                              void* d_out, int out_size, void* d_ws, size_t ws_size,
                              hipStream_t stream) {
    const float* x = (const float*)d_in[0];     // [B,T,D] fp32
    const float* emb = (const float*)d_in[1];   // [K,D] fp32
    const int nrows = in_sizes[0] / D;          // 131072

    float* out_q = (float*)d_out;
    float* out_idx = out_q + (size_t)nrows * D;
    float* out_loss = out_idx + nrows;

    char* ws = (char*)d_ws;
    float* e2 = (float*)(ws + WS_E2);
    unsigned short* ehi = (unsigned short*)(ws + WS_EHI);
    unsigned short* elo = (unsigned short*)(ws + WS_ELO);
    unsigned int* counter = (unsigned int*)(ws + WS_CNT);
    int* flaglist = (int*)(ws + WS_FLAGS);

    prep_kernel<<<(KCODES * D) / 256, 256, 0, stream>>>(emb, e2, ehi, elo, counter);
    vq_kernel<<<nrows / 128, 256, 0, stream>>>(x, emb, e2, ehi, elo, out_q,
                                               out_idx, out_loss, counter, flaglist);
    rescore_kernel<<<2048, 256, 0, stream>>>(x, emb, e2, out_q, out_idx, out_loss,
                                             counter, flaglist);
}